// Round 13
// baseline (270.329 us; speedup 1.0000x reference)
//
#include <hip/hip_runtime.h>

// GRU stack, hidden_size=1, 6 layers, B=4096, T=2048, D=8.
// One 8-lane group runs TWO independent batch chains (A: b, B: b+2048),
// source-interleaved: chain B's issue fills chain A's trans-latency stalls
// (r12 showed wall ~= serial-trans chain ~164cy with issue ~85cy; two lean
// chains -> step-pair ~= max(2*issue, chain) ~= half the per-step cost).
// r8's version of this failed because its fat step had per-step LDS waits
// (serialize instruction stream, counted x2); this step has ZERO LDS ops.
//
// Lanes 0..5 = layers (skewed pipeline): layer l at iter i handles t = i-l;
// prev layer's h via DPP row_shr:1 (row-crossing lanes are l==0 -> ignored).
// Layer-0 projection: distributed dots (lane j = step j) one chunk ahead,
// brought to lane 8g by STATIC row_shl:s DPP + select, one slot per step
// (r12). Pipeline: load(c+4) | dots(c+2) | presel(c+1) | run(c).
//
// Gate math, constants pre-folded (c1=-log2e, cz=+log2e, c2=-2log2e):
//   r = rcp(1+exp2(c1*p)); zbar via cz; merged rcp:
//   hn = h + R*((1-h) - (1+h)*en), R = rcp((1+en)(1+ez)), P=fma(en,pz1,pz1)

#define T_LEN 2048
#define T8    (T_LEN * 8)
#define NCH   256          // 8-step chunks

typedef __attribute__((ext_vector_type(2))) float v2f;

__device__ __forceinline__ float dpp_shr1(float v) {   // lane i <- lane i-1
    int i = __builtin_bit_cast(int, v);
    int r = __builtin_amdgcn_update_dpp(0, i, 0x111, 0xF, 0xF, true);
    return __builtin_bit_cast(float, r);
}

// static row_shl:S (lane i <- lane i+S), S literal 1..7
#define DPPSHL(S, v) __builtin_bit_cast(float,                                \
    __builtin_amdgcn_update_dpp(0, __builtin_bit_cast(int, (v)),              \
                                0x100 | ((S) == 0 ? 1 : (S)), 0xF, 0xF, true))
#define DPPSHLX(S, v) ((S) == 0 ? (v) : DPPSHL(S, v))

__global__ __launch_bounds__(64)
__attribute__((amdgpu_waves_per_eu(1, 1)))
void gru_scan(const float* __restrict__ x,
              const float* __restrict__ Wih0,   // [3][8]
              const float* __restrict__ Wrest,  // [5][3]
              const float* __restrict__ Whh,    // [6][3]
              const float* __restrict__ bih,    // [6][3]
              const float* __restrict__ bhh,    // [6][3]
              float* __restrict__ out)          // [B]
{
    const int lane = threadIdx.x & 63;   // block = 1 wave
    const int l    = lane & 7;           // 0..5 layers; 6,7 proj helpers
    const int g    = lane >> 3;          // group within wave
    const int bA   = blockIdx.x * 8 + g; // chain A batch
    const int bB   = bA + 2048;          // chain B batch

    const float c1 = -1.44269504088896340736f;   // -log2(e)  [r gate]
    const float cz =  1.44269504088896340736f;   // +log2(e)  [zbar gate]
    const float c2 = 2.0f * c1;                  // [n gate]

    const int  lidx = l < 6 ? l : 5;
    const bool lz   = (l == 0);
    const float m1  = lz ? 0.0f : 1.0f;

    const float whpr = c1 * Whh[lidx * 3 + 0];
    const float whpz = cz * Whh[lidx * 3 + 1];
    const float whpn = c2 * Whh[lidx * 3 + 2];
    const float bhpn = c2 * bhh[lidx * 3 + 2];
    const v2f  WH12 = {whpr, whpz};

    const int ir = lidx >= 1 ? lidx - 1 : 0;
    const float W1r = m1 * c1 * Wrest[ir * 3 + 0];
    const float W1z = m1 * cz * Wrest[ir * 3 + 1];
    const float W1n = m1 * c2 * Wrest[ir * 3 + 2];
    const v2f  W1rz = {W1r, W1z};
    const float B1r = c1 * (bih[lidx * 3 + 0] + bhh[lidx * 3 + 0]);
    const float B1z = cz * (bih[lidx * 3 + 1] + bhh[lidx * 3 + 1]);
    const float B1n = c2 *  bih[lidx * 3 + 2];
    const v2f  B1rz = {B1r, B1z};

    // layer-0 projection constants (uniform)
    const v2f  B0rz = {c1 * (bih[0] + bhh[0]), cz * (bih[1] + bhh[1])};
    const float B0n = c2 * bih[2];
    v2f  wrz[8];
    float wn[8];
    #pragma unroll
    for (int d = 0; d < 8; ++d) {
        wrz[d] = (v2f){c1 * Wih0[d], cz * Wih0[8 + d]};
        wn[d]  = c2 * Wih0[16 + d];
    }

    // lane j of a group loads only step j's 32B of each chunk
    const float4* xpA = reinterpret_cast<const float4*>(x + (size_t)bA * T8) + (lane & 7) * 2;
    const float4* xpB = reinterpret_cast<const float4*>(x + (size_t)bB * T8) + (lane & 7) * 2;

    // L buffers: chunk c -> slot c&3, per chain
    float4 LA0a, LA0b, LA1a, LA1b, LA2a, LA2b, LA3a, LA3b;
    float4 LB0a, LB0b, LB1a, LB1b, LB2a, LB2b, LB3a, LB3b;
    // dot accumulators: chunk c -> PZ[c&1], per chain
    v2f   PZAArz, PZABrz, PZBArz, PZBBrz;   // PZ<chain><slot>
    float PZAAn,  PZABn,  PZBAn,  PZBBn;
    // preselected per-step gate bases: chunk c -> S[c&1], per chain
    v2f   SrzAA[8], SrzAB[8], SrzBA[8], SrzBB[8];
    float SnAA[8],  SnAB[8],  SnBA[8],  SnBB[8];
    float hA = 0.0f, hB = 0.0f;

#define LOADL(P, A, B, C)                                                     \
    { const int cc_ = ((C) < NCH) ? (C) : 0;                                  \
      const float4* p_ = P + (size_t)cc_ * 16;                                \
      A = p_[0]; B = p_[1]; }

#define GETF(S, A, B) ((S)==0?(A).x:(S)==1?(A).y:(S)==2?(A).z:(S)==3?(A).w:  \
                       (S)==4?(B).x:(S)==5?(B).y:(S)==6?(B).z:(B).w)

#define DOT_SLICE(S, LA, LB, PRZ, PN)                                         \
    { const float xv_ = GETF(S, LA, LB);                                      \
      if ((S) == 0) { PRZ = wrz[0] * (v2f){xv_, xv_} + B0rz;                  \
                      PN  = fmaf(xv_, wn[0], B0n); }                          \
      else          { PRZ = wrz[S] * (v2f){xv_, xv_} + PRZ;                   \
                      PN  = fmaf(xv_, wn[S], PN); } }

#define PRESEL(S, SRZ, SN, PRZs, PNs)                                         \
    { const float br_ = DPPSHLX(S, (PRZs).x);                                 \
      const float bz_ = DPPSHLX(S, (PRZs).y);                                 \
      const float bn_ = DPPSHLX(S, (PNs));                                    \
      SRZ[S] = (v2f){lz ? br_ : B1r, lz ? bz_ : B1z};                         \
      SN[S]  = lz ? bn_ : B1n; }

    // two independent GRU steps, source-interleaved for ILP
    auto step2 = [&](int i, v2f brzA, float bnA, v2f brzB, float bnB, bool guard) {
        const float nbrA = dpp_shr1(hA);
        const float nbrB = dpp_shr1(hB);

        const v2f t12A = WH12 * (v2f){hA, hA} + brzA;
        const v2f t12B = WH12 * (v2f){hB, hB} + brzB;
        const v2f arzA = W1rz * (v2f){nbrA, nbrA} + t12A;
        const v2f arzB = W1rz * (v2f){nbrB, nbrB} + t12B;

        const float erA = __builtin_amdgcn_exp2f(arzA.x);
        const float erB = __builtin_amdgcn_exp2f(arzB.x);
        const float ezA = __builtin_amdgcn_exp2f(arzA.y);
        const float ezB = __builtin_amdgcn_exp2f(arzB.y);
        const float rA  = __builtin_amdgcn_rcpf(1.0f + erA);
        const float rB  = __builtin_amdgcn_rcpf(1.0f + erB);
        const float pz1A = 1.0f + ezA;
        const float pz1B = 1.0f + ezB;

        const v2f tnxA = (v2f){whpn, W1n} * (v2f){hA, nbrA} + (v2f){bhpn, bnA};
        const v2f tnxB = (v2f){whpn, W1n} * (v2f){hB, nbrB} + (v2f){bhpn, bnB};
        const float naA = fmaf(rA, tnxA.x, tnxA.y);
        const float naB = fmaf(rB, tnxB.x, tnxB.y);
        const float enA = __builtin_amdgcn_exp2f(naA);
        const float enB = __builtin_amdgcn_exp2f(naB);

        const float PA = fmaf(enA, pz1A, pz1A);        // (1+en)(1+ez)
        const float PB = fmaf(enB, pz1B, pz1B);
        const float RA = __builtin_amdgcn_rcpf(PA);
        const float RB = __builtin_amdgcn_rcpf(PB);

        const float hp1A = hA + 1.0f;
        const float hp1B = hB + 1.0f;
        const float hm1A = 1.0f - hA;
        const float hm1B = 1.0f - hB;
        const float qA = fmaf(-hp1A, enA, hm1A);
        const float qB = fmaf(-hp1B, enB, hm1B);
        const float hnA = fmaf(RA, qA, hA);
        const float hnB = fmaf(RB, qB, hB);

        if (guard) {
            const bool ok = (unsigned)(i - l) < (unsigned)T_LEN;
            hA = ok ? hnA : hA;
            hB = ok ? hnB : hB;
        } else {
            hA = hnA;
            hB = hnB;
        }
    };

    // fused step-pair: chains + dot slices (chunk c+2) + presel (chunk c+1)
#define STEPX2(S, C, Sb, So, GD)                                              \
    { step2((C) * 8 + (S), SrzA##Sb[S], SnA##Sb[S], SrzB##Sb[S], SnB##Sb[S], GD); \
      DOT_SLICE(S, LA##Sb##a_, LA##Sb##b_, PZA##Sb##rz_, PZA##Sb##n_)         \
      PRESEL(S, SrzA##So, SnA##So, PZA##So##rz_, PZA##So##n_)                 \
      DOT_SLICE(S, LB##Sb##a_, LB##Sb##b_, PZB##Sb##rz_, PZB##Sb##n_)         \
      PRESEL(S, SrzB##So, SnB##So, PZB##So##rz_, PZB##So##n_) }

    // RUN_CHUNK2(C, rd, wr, LN(dots-src chunk c+2 slot), Ll(load-dst slot), C4, GD)
#define RUN_CHUNK2(C, RD, WR, LN, LL, C4, GD)                                 \
    { LOADL(xpA, LA##LL##a, LA##LL##b, C4)                                    \
      LOADL(xpB, LB##LL##a, LB##LL##b, C4)                                    \
      STEPX2_ALL(C, RD, WR, LN, GD) }

    // helper aliases to wire S-slot (A/B = c&1) and L-slot (0..3) names
#define STEPX2_ALL(C, RD, WR, LN, GD)                                         \
    { auto& LA##RD##a_ = LA##LN##a; auto& LA##RD##b_ = LA##LN##b;             \
      auto& LB##RD##a_ = LB##LN##a; auto& LB##RD##b_ = LB##LN##b;             \
      auto& PZA##RD##rz_ = PZA##RD##rz; auto& PZA##RD##n_ = PZA##RD##n;       \
      auto& PZB##RD##rz_ = PZB##RD##rz; auto& PZB##RD##n_ = PZB##RD##n;       \
      auto& PZA##WR##rz_ = PZA##WR##rz; auto& PZA##WR##n_ = PZA##WR##n;       \
      auto& PZB##WR##rz_ = PZB##WR##rz; auto& PZB##WR##n_ = PZB##WR##n;       \
      STEPX2_8(C, RD, WR, GD) }

    // NOTE: macro name juggling above is error-prone; do it explicitly instead.
#undef STEPX2
#undef RUN_CHUNK2
#undef STEPX2_ALL

    // explicit fused step-pair
#define FSTEP(S, C, SRZA, SNA, SRZB, SNB,                 /* read S slot */   \
              LNAa, LNAb, LNBa, LNBb, PZWArz, PZWAn, PZWBrz, PZWBn, /* dots */\
              SWA, SWNA, SWB, SWNB, PZRArz, PZRAn, PZRBrz, PZRBn,  /* presel */\
              GD)                                                             \
    { step2((C) * 8 + (S), SRZA[S], SNA[S], SRZB[S], SNB[S], GD);             \
      DOT_SLICE(S, LNAa, LNAb, PZWArz, PZWAn)                                 \
      DOT_SLICE(S, LNBa, LNBb, PZWBrz, PZWBn)                                 \
      PRESEL(S, SWA, SWNA, PZRArz, PZRAn)                                     \
      PRESEL(S, SWB, SWNB, PZRBrz, PZRBn) }

#define RUNC(C, SRZA, SNA, SRZB, SNB, LNAa, LNAb, LNBa, LNBb,                 \
             PZWArz, PZWAn, PZWBrz, PZWBn, SWA, SWNA, SWB, SWNB,              \
             PZRArz, PZRAn, PZRBrz, PZRBn, LLAa, LLAb, LLBa, LLBb, C4, GD)    \
    { LOADL(xpA, LLAa, LLAb, C4) LOADL(xpB, LLBa, LLBb, C4)                   \
      FSTEP(0, C, SRZA, SNA, SRZB, SNB, LNAa, LNAb, LNBa, LNBb, PZWArz, PZWAn, PZWBrz, PZWBn, SWA, SWNA, SWB, SWNB, PZRArz, PZRAn, PZRBrz, PZRBn, GD) \
      FSTEP(1, C, SRZA, SNA, SRZB, SNB, LNAa, LNAb, LNBa, LNBb, PZWArz, PZWAn, PZWBrz, PZWBn, SWA, SWNA, SWB, SWNB, PZRArz, PZRAn, PZRBrz, PZRBn, GD) \
      FSTEP(2, C, SRZA, SNA, SRZB, SNB, LNAa, LNAb, LNBa, LNBb, PZWArz, PZWAn, PZWBrz, PZWBn, SWA, SWNA, SWB, SWNB, PZRArz, PZRAn, PZRBrz, PZRBn, GD) \
      FSTEP(3, C, SRZA, SNA, SRZB, SNB, LNAa, LNAb, LNBa, LNBb, PZWArz, PZWAn, PZWBrz, PZWBn, SWA, SWNA, SWB, SWNB, PZRArz, PZRAn, PZRBrz, PZRBn, GD) \
      FSTEP(4, C, SRZA, SNA, SRZB, SNB, LNAa, LNAb, LNBa, LNBb, PZWArz, PZWAn, PZWBrz, PZWBn, SWA, SWNA, SWB, SWNB, PZRArz, PZRAn, PZRBrz, PZRBn, GD) \
      FSTEP(5, C, SRZA, SNA, SRZB, SNB, LNAa, LNAb, LNBa, LNBb, PZWArz, PZWAn, PZWBrz, PZWBn, SWA, SWNA, SWB, SWNB, PZRArz, PZRAn, PZRBrz, PZRBn, GD) \
      FSTEP(6, C, SRZA, SNA, SRZB, SNB, LNAa, LNAb, LNBa, LNBb, PZWArz, PZWAn, PZWBrz, PZWBn, SWA, SWNA, SWB, SWNB, PZRArz, PZRAn, PZRBrz, PZRBn, GD) \
      FSTEP(7, C, SRZA, SNA, SRZB, SNB, LNAa, LNAb, LNBa, LNBb, PZWArz, PZWAn, PZWBrz, PZWBn, SWA, SWNA, SWB, SWNB, PZRArz, PZRAn, PZRBrz, PZRBn, GD) }

    // ---- prologue: L slots 0..3 <- chunks 0..3; dots(0)->PZ*A, dots(1)->PZ*B;
    //      presel(0)->S*A ----
    LOADL(xpA, LA0a, LA0b, 0) LOADL(xpB, LB0a, LB0b, 0)
    LOADL(xpA, LA1a, LA1b, 1) LOADL(xpB, LB1a, LB1b, 1)
    LOADL(xpA, LA2a, LA2b, 2) LOADL(xpB, LB2a, LB2b, 2)
    LOADL(xpA, LA3a, LA3b, 3) LOADL(xpB, LB3a, LB3b, 3)

#define DOT8(LA, LB, PRZ, PN)                                                 \
    DOT_SLICE(0, LA, LB, PRZ, PN) DOT_SLICE(1, LA, LB, PRZ, PN)               \
    DOT_SLICE(2, LA, LB, PRZ, PN) DOT_SLICE(3, LA, LB, PRZ, PN)               \
    DOT_SLICE(4, LA, LB, PRZ, PN) DOT_SLICE(5, LA, LB, PRZ, PN)               \
    DOT_SLICE(6, LA, LB, PRZ, PN) DOT_SLICE(7, LA, LB, PRZ, PN)

#define PRESEL8(SRZ, SN, PRZ, PN)                                             \
    PRESEL(0, SRZ, SN, PRZ, PN) PRESEL(1, SRZ, SN, PRZ, PN)                   \
    PRESEL(2, SRZ, SN, PRZ, PN) PRESEL(3, SRZ, SN, PRZ, PN)                   \
    PRESEL(4, SRZ, SN, PRZ, PN) PRESEL(5, SRZ, SN, PRZ, PN)                   \
    PRESEL(6, SRZ, SN, PRZ, PN) PRESEL(7, SRZ, SN, PRZ, PN)

    DOT8(LA0a, LA0b, PZAArz, PZAAn) DOT8(LB0a, LB0b, PZBArz, PZBAn)
    DOT8(LA1a, LA1b, PZABrz, PZABn) DOT8(LB1a, LB1b, PZBBrz, PZBBn)
    PRESEL8(SrzAA, SnAA, PZAArz, PZAAn) PRESEL8(SrzBA, SnBA, PZBArz, PZBAn)

    // ---- chunks 0..3 (chunk 0 guarded) ----
    RUNC(0, SrzAA, SnAA, SrzBA, SnBA, LA2a, LA2b, LB2a, LB2b,
         PZAArz, PZAAn, PZBArz, PZBAn, SrzAB, SnAB, SrzBB, SnBB,
         PZABrz, PZABn, PZBBrz, PZBBn, LA0a, LA0b, LB0a, LB0b, 4, true)
    RUNC(1, SrzAB, SnAB, SrzBB, SnBB, LA3a, LA3b, LB3a, LB3b,
         PZABrz, PZABn, PZBBrz, PZBBn, SrzAA, SnAA, SrzBA, SnBA,
         PZAArz, PZAAn, PZBArz, PZBAn, LA1a, LA1b, LB1a, LB1b, 5, false)
    RUNC(2, SrzAA, SnAA, SrzBA, SnBA, LA0a, LA0b, LB0a, LB0b,
         PZAArz, PZAAn, PZBArz, PZBAn, SrzAB, SnAB, SrzBB, SnBB,
         PZABrz, PZABn, PZBBrz, PZBBn, LA2a, LA2b, LB2a, LB2b, 6, false)
    RUNC(3, SrzAB, SnAB, SrzBB, SnBB, LA1a, LA1b, LB1a, LB1b,
         PZABrz, PZABn, PZBBrz, PZBBn, SrzAA, SnAA, SrzBA, SnBA,
         PZAArz, PZAAn, PZBArz, PZBAn, LA3a, LA3b, LB3a, LB3b, 7, false)

    #pragma unroll 1
    for (int q = 1; q < 64; ++q) {
        const int c0 = q * 4;
        RUNC(c0 + 0, SrzAA, SnAA, SrzBA, SnBA, LA2a, LA2b, LB2a, LB2b,
             PZAArz, PZAAn, PZBArz, PZBAn, SrzAB, SnAB, SrzBB, SnBB,
             PZABrz, PZABn, PZBBrz, PZBBn, LA0a, LA0b, LB0a, LB0b, c0 + 4, false)
        RUNC(c0 + 1, SrzAB, SnAB, SrzBB, SnBB, LA3a, LA3b, LB3a, LB3b,
             PZABrz, PZABn, PZBBrz, PZBBn, SrzAA, SnAA, SrzBA, SnBA,
             PZAArz, PZAAn, PZBArz, PZBAn, LA1a, LA1b, LB1a, LB1b, c0 + 5, false)
        RUNC(c0 + 2, SrzAA, SnAA, SrzBA, SnBA, LA0a, LA0b, LB0a, LB0b,
             PZAArz, PZAAn, PZBArz, PZBAn, SrzAB, SnAB, SrzBB, SnBB,
             PZABrz, PZABn, PZBBrz, PZBBn, LA2a, LA2b, LB2a, LB2b, c0 + 6, false)
        RUNC(c0 + 3, SrzAB, SnAB, SrzBB, SnBB, LA1a, LA1b, LB1a, LB1b,
             PZABrz, PZABn, PZBBrz, PZBBn, SrzAA, SnAA, SrzBA, SnBA,
             PZAArz, PZAAn, PZBArz, PZBAn, LA3a, LA3b, LB3a, LB3b, c0 + 7, false)
    }

    // tail: 5 guarded steps, no x (layer 0 frozen; layers 1..5 finish)
    #pragma unroll
    for (int i = T_LEN; i < T_LEN + 5; ++i)
        step2(i, B1rz, B1n, B1rz, B1n, true);

    if (l == 5) {
        out[bA] = hA;    // layer-5 h frozen at t = T-1
        out[bB] = hB;
    }
}

extern "C" void kernel_launch(void* const* d_in, const int* in_sizes, int n_in,
                              void* d_out, int out_size, void* d_ws, size_t ws_size,
                              hipStream_t stream) {
    const float* x     = (const float*)d_in[0];
    const float* Wih0  = (const float*)d_in[1];
    const float* Wrest = (const float*)d_in[2];
    const float* Whh   = (const float*)d_in[3];
    const float* bih   = (const float*)d_in[4];
    const float* bhh   = (const float*)d_in[5];
    float* out = (float*)d_out;

    gru_scan<<<256, 64, 0, stream>>>(x, Wih0, Wrest, Whh, bih, bhh, out);
}

// Round 14
// 262.087 us; speedup vs baseline: 1.0314x; 1.0314x over previous
//
#include <hip/hip_runtime.h>

// GRU stack, hidden_size=1, 6 layers, B=4096, T=2048, D=8.
// One 8-lane group runs TWO batch chains (A: b, B: b+2048) PACKED into v2f:
// every chain op is a single v_pk_fma/pk_add over (A,B) -- the compiler
// cannot serialize the pair (r13's failure: scheduler re-serialized two
// scalar chains to hold a 132-VGPR occupancy target). Only the 4 trans
// stages (exp2/rcp) split into x2 scalar ops; their latencies overlap, so
// step-pair ~= chain(170cy) + 4x8cy ~= 205cy -> ~100cy/step (r12: 173).
// __launch_bounds__(64, 1): min-waves/EU=1 -> full 512-VGPR budget (the
// amdgpu_waves_per_eu attribute was demonstrably not taking effect).
//
// Lanes 0..5 = layers (skewed pipeline): layer l at iter i handles t = i-l;
// prev layer's h via DPP row_shr:1. Layer-0 projection: distributed dots
// (lane j = step j) one chunk ahead; STATIC row_shl:s DPP + select presel
// into single-buffered S[8] (read-before-write per slot). L depth 3.
// Pipeline: load(c+3) | dots(c+2) | presel(c+1) | run(c).
//
// Gate math, constants pre-folded (c1=-log2e, cz=+log2e, c2=-2log2e):
//   r = rcp(1+exp2(.)); zbar via cz; merged rcp:
//   hn = h + R*((1-h) - (1+h)*en), R = rcp((1+en)(1+ez)), P=fma(en,pz1,pz1)

#define T_LEN 2048
#define T8    (T_LEN * 8)
#define NCH   256          // 8-step chunks

typedef __attribute__((ext_vector_type(2))) float v2f;

__device__ __forceinline__ float dpp_shr1(float v) {   // lane i <- lane i-1
    int i = __builtin_bit_cast(int, v);
    int r = __builtin_amdgcn_update_dpp(0, i, 0x111, 0xF, 0xF, true);
    return __builtin_bit_cast(float, r);
}

// static row_shl:S (lane i <- lane i+S), S literal 1..7
#define DPPSHL(S, v) __builtin_bit_cast(float,                                \
    __builtin_amdgcn_update_dpp(0, __builtin_bit_cast(int, (v)),              \
                                0x100 | ((S) == 0 ? 1 : (S)), 0xF, 0xF, true))
#define DPPSHLX(S, v) ((S) == 0 ? (v) : DPPSHL(S, v))

__global__ __launch_bounds__(64, 1)
void gru_scan(const float* __restrict__ x,
              const float* __restrict__ Wih0,   // [3][8]
              const float* __restrict__ Wrest,  // [5][3]
              const float* __restrict__ Whh,    // [6][3]
              const float* __restrict__ bih,    // [6][3]
              const float* __restrict__ bhh,    // [6][3]
              float* __restrict__ out)          // [B]
{
    const int lane = threadIdx.x & 63;   // block = 1 wave
    const int l    = lane & 7;           // 0..5 layers; 6,7 proj helpers
    const int g    = lane >> 3;          // group within wave
    const int bA   = blockIdx.x * 8 + g; // chain A batch
    const int bB   = bA + 2048;          // chain B batch

    const float c1 = -1.44269504088896340736f;   // -log2(e)  [r gate]
    const float cz =  1.44269504088896340736f;   // +log2(e)  [zbar gate]
    const float c2 = 2.0f * c1;                  // [n gate]

    const int  lidx = l < 6 ? l : 5;
    const bool lz   = (l == 0);
    const float m1  = lz ? 0.0f : 1.0f;

    const float whpr = c1 * Whh[lidx * 3 + 0];
    const float whpz = cz * Whh[lidx * 3 + 1];
    const float whpn = c2 * Whh[lidx * 3 + 2];
    const float bhpn = c2 * bhh[lidx * 3 + 2];

    const int ir = lidx >= 1 ? lidx - 1 : 0;
    const float W1r = m1 * c1 * Wrest[ir * 3 + 0];
    const float W1z = m1 * cz * Wrest[ir * 3 + 1];
    const float W1n = m1 * c2 * Wrest[ir * 3 + 2];
    const float B1r = c1 * (bih[lidx * 3 + 0] + bhh[lidx * 3 + 0]);
    const float B1z = cz * (bih[lidx * 3 + 1] + bhh[lidx * 3 + 1]);
    const float B1n = c2 *  bih[lidx * 3 + 2];

    // packed (same value in both halves -- both chains share lane weights)
    const v2f WHPR2 = {whpr, whpr}, WHPZ2 = {whpz, whpz};
    const v2f WHPN2 = {whpn, whpn}, BHPN2 = {bhpn, bhpn};
    const v2f W1R2  = {W1r, W1r},   W1Z2  = {W1z, W1z},  W1N2 = {W1n, W1n};
    const v2f B1R2  = {B1r, B1r},   B1Z2  = {B1z, B1z},  B1N2 = {B1n, B1n};

    // layer-0 projection constants (uniform)
    const v2f  B0rz = {c1 * (bih[0] + bhh[0]), cz * (bih[1] + bhh[1])};
    const float B0n = c2 * bih[2];
    v2f  wrz[8];
    float wn[8];
    #pragma unroll
    for (int d = 0; d < 8; ++d) {
        wrz[d] = (v2f){c1 * Wih0[d], cz * Wih0[8 + d]};
        wn[d]  = c2 * Wih0[16 + d];
    }

    // lane j of a group loads only step j's 32B of each chunk
    const float4* xpA = reinterpret_cast<const float4*>(x + (size_t)bA * T8) + (lane & 7) * 2;
    const float4* xpB = reinterpret_cast<const float4*>(x + (size_t)bB * T8) + (lane & 7) * 2;

    // L buffers, depth 3: slot s holds chunk c with c%3 == s (per chain)
    float4 LA0a, LA0b, LA1a, LA1b, LA2a, LA2b;
    float4 LB0a, LB0b, LB1a, LB1b, LB2a, LB2b;
    // dot accumulators: chunk c -> slot c%2, per chain (rz packed, n scalar)
    v2f   PZArz0, PZArz1, PZBrz0, PZBrz1;
    float PZAn0,  PZAn1,  PZBn0,  PZBn1;
    // single-buffered per-step gate bases, packed (A,B)
    v2f Sr[8], Sz[8], Sn[8];
    v2f h = {0.0f, 0.0f};

#define LOADL(P, A, B, C)                                                     \
    { const int cc_ = ((C) < NCH) ? (C) : 0;                                  \
      const float4* p_ = P + (size_t)cc_ * 16;                                \
      A = p_[0]; B = p_[1]; }

#define GETF(S, A, B) ((S)==0?(A).x:(S)==1?(A).y:(S)==2?(A).z:(S)==3?(A).w:  \
                       (S)==4?(B).x:(S)==5?(B).y:(S)==6?(B).z:(B).w)

    // dot slice S: lane j accumulates dimension S of its step-j projection
#define DOT_SLICE(S, LA, LB, PRZ, PN)                                         \
    { const float xv_ = GETF(S, LA, LB);                                      \
      if ((S) == 0) { PRZ = wrz[0] * (v2f){xv_, xv_} + B0rz;                  \
                      PN  = fmaf(xv_, wn[0], B0n); }                          \
      else          { PRZ = wrz[S] * (v2f){xv_, xv_} + PRZ;                   \
                      PN  = fmaf(xv_, wn[S], PN); } }

    // presel slot S (packed): static shl:S brings proj(step S) to lane 8g
#define PRESELP(S, PZArz, PZAn, PZBrz, PZBn)                                  \
    { const float brA_ = DPPSHLX(S, (PZArz).x);                               \
      const float bzA_ = DPPSHLX(S, (PZArz).y);                               \
      const float bnA_ = DPPSHLX(S, (PZAn));                                  \
      const float brB_ = DPPSHLX(S, (PZBrz).x);                               \
      const float bzB_ = DPPSHLX(S, (PZBrz).y);                               \
      const float bnB_ = DPPSHLX(S, (PZBn));                                  \
      Sr[S] = (v2f){lz ? brA_ : B1r, lz ? brB_ : B1r};                        \
      Sz[S] = (v2f){lz ? bzA_ : B1z, lz ? bzB_ : B1z};                        \
      Sn[S] = (v2f){lz ? bnA_ : B1n, lz ? bnB_ : B1n}; }

    // packed GRU step: both chains advance in pk ops; trans split x2
    auto stepP = [&](int i, v2f br, v2f bz, v2f bn, bool guard) {
        const v2f nbr = {dpp_shr1(h.x), dpp_shr1(h.y)};
        const v2f one = {1.0f, 1.0f};

        const v2f tr = WHPR2 * h + br;
        const v2f ar = W1R2 * nbr + tr;
        const v2f tz = WHPZ2 * h + bz;
        const v2f az = W1Z2 * nbr + tz;

        const v2f er = {__builtin_amdgcn_exp2f(ar.x), __builtin_amdgcn_exp2f(ar.y)};
        const v2f ez = {__builtin_amdgcn_exp2f(az.x), __builtin_amdgcn_exp2f(az.y)};
        const v2f pr1 = one + er;
        const v2f r  = {__builtin_amdgcn_rcpf(pr1.x), __builtin_amdgcn_rcpf(pr1.y)};
        const v2f pz1 = one + ez;

        const v2f tn  = WHPN2 * h + BHPN2;
        const v2f xnp = W1N2 * nbr + bn;
        const v2f na  = r * tn + xnp;
        const v2f en  = {__builtin_amdgcn_exp2f(na.x), __builtin_amdgcn_exp2f(na.y)};

        const v2f P = en * pz1 + pz1;               // (1+en)(1+ez)
        const v2f R = {__builtin_amdgcn_rcpf(P.x), __builtin_amdgcn_rcpf(P.y)};

        const v2f hp1 = h + one;
        const v2f hm1 = one - h;
        const v2f q   = hm1 - hp1 * en;
        const v2f hn  = R * q + h;                  // h + R*q

        if (guard) {
            const bool ok = (unsigned)(i - l) < (unsigned)T_LEN;
            h.x = ok ? hn.x : h.x;
            h.y = ok ? hn.y : h.y;
        } else {
            h = hn;
        }
    };

    // fused step: packed chain + dots (chunk c+2, both chains) + presel (c+1)
#define FSTEPP(S, C, LAra, LArb, LBra, LBrb,                                  \
               PZWArz, PZWAn, PZWBrz, PZWBn, PZRArz, PZRAn, PZRBrz, PZRBn, GD)\
    { stepP((C) * 8 + (S), Sr[S], Sz[S], Sn[S], GD);                          \
      DOT_SLICE(S, LAra, LArb, PZWArz, PZWAn)                                 \
      DOT_SLICE(S, LBra, LBrb, PZWBrz, PZWBn)                                 \
      PRESELP(S, PZRArz, PZRAn, PZRBrz, PZRBn) }

#define RUNCP(C, LAra, LArb, LBra, LBrb, LAla, LAlb, LBla, LBlb,              \
              PZWArz, PZWAn, PZWBrz, PZWBn, PZRArz, PZRAn, PZRBrz, PZRBn, C3, GD) \
    { LOADL(xpA, LAla, LAlb, C3) LOADL(xpB, LBla, LBlb, C3)                   \
      FSTEPP(0, C, LAra, LArb, LBra, LBrb, PZWArz, PZWAn, PZWBrz, PZWBn, PZRArz, PZRAn, PZRBrz, PZRBn, GD) \
      FSTEPP(1, C, LAra, LArb, LBra, LBrb, PZWArz, PZWAn, PZWBrz, PZWBn, PZRArz, PZRAn, PZRBrz, PZRBn, GD) \
      FSTEPP(2, C, LAra, LArb, LBra, LBrb, PZWArz, PZWAn, PZWBrz, PZWBn, PZRArz, PZRAn, PZRBrz, PZRBn, GD) \
      FSTEPP(3, C, LAra, LArb, LBra, LBrb, PZWArz, PZWAn, PZWBrz, PZWBn, PZRArz, PZRAn, PZRBrz, PZRBn, GD) \
      FSTEPP(4, C, LAra, LArb, LBra, LBrb, PZWArz, PZWAn, PZWBrz, PZWBn, PZRArz, PZRAn, PZRBrz, PZRBn, GD) \
      FSTEPP(5, C, LAra, LArb, LBra, LBrb, PZWArz, PZWAn, PZWBrz, PZWBn, PZRArz, PZRAn, PZRBrz, PZRBn, GD) \
      FSTEPP(6, C, LAra, LArb, LBra, LBrb, PZWArz, PZWAn, PZWBrz, PZWBn, PZRArz, PZRAn, PZRBrz, PZRBn, GD) \
      FSTEPP(7, C, LAra, LArb, LBra, LBrb, PZWArz, PZWAn, PZWBrz, PZWBn, PZRArz, PZRAn, PZRBrz, PZRBn, GD) }

    // ---- prologue: slots 0,1,2 <- chunks 0,1,2; dots(0)->PZ*0, dots(1)->PZ*1;
    //      presel(0) -> S ----
    LOADL(xpA, LA0a, LA0b, 0) LOADL(xpB, LB0a, LB0b, 0)
    LOADL(xpA, LA1a, LA1b, 1) LOADL(xpB, LB1a, LB1b, 1)
    LOADL(xpA, LA2a, LA2b, 2) LOADL(xpB, LB2a, LB2b, 2)

#define DOT8(LA, LB, PRZ, PN)                                                 \
    DOT_SLICE(0, LA, LB, PRZ, PN) DOT_SLICE(1, LA, LB, PRZ, PN)               \
    DOT_SLICE(2, LA, LB, PRZ, PN) DOT_SLICE(3, LA, LB, PRZ, PN)               \
    DOT_SLICE(4, LA, LB, PRZ, PN) DOT_SLICE(5, LA, LB, PRZ, PN)               \
    DOT_SLICE(6, LA, LB, PRZ, PN) DOT_SLICE(7, LA, LB, PRZ, PN)

    DOT8(LA0a, LA0b, PZArz0, PZAn0) DOT8(LB0a, LB0b, PZBrz0, PZBn0)
    DOT8(LA1a, LA1b, PZArz1, PZAn1) DOT8(LB1a, LB1b, PZBrz1, PZBn1)

    PRESELP(0, PZArz0, PZAn0, PZBrz0, PZBn0)
    PRESELP(1, PZArz0, PZAn0, PZBrz0, PZBn0)
    PRESELP(2, PZArz0, PZAn0, PZBrz0, PZBn0)
    PRESELP(3, PZArz0, PZAn0, PZBrz0, PZBn0)
    PRESELP(4, PZArz0, PZAn0, PZBrz0, PZBn0)
    PRESELP(5, PZArz0, PZAn0, PZBrz0, PZBn0)
    PRESELP(6, PZArz0, PZAn0, PZBrz0, PZBn0)
    PRESELP(7, PZArz0, PZAn0, PZBrz0, PZBn0)

    // slot schedule (c: rd=(c+2)%3, ld=c%3, PZw=c%2, PZr=(c+1)%2)
    // ---- chunks 0..3 explicit (chunk 0 guarded) ----
    RUNCP(0, LA2a, LA2b, LB2a, LB2b, LA0a, LA0b, LB0a, LB0b,
          PZArz0, PZAn0, PZBrz0, PZBn0, PZArz1, PZAn1, PZBrz1, PZBn1, 3, true)
    RUNCP(1, LA0a, LA0b, LB0a, LB0b, LA1a, LA1b, LB1a, LB1b,
          PZArz1, PZAn1, PZBrz1, PZBn1, PZArz0, PZAn0, PZBrz0, PZBn0, 4, false)
    RUNCP(2, LA1a, LA1b, LB1a, LB1b, LA2a, LA2b, LB2a, LB2b,
          PZArz0, PZAn0, PZBrz0, PZBn0, PZArz1, PZAn1, PZBrz1, PZBn1, 5, false)
    RUNCP(3, LA2a, LA2b, LB2a, LB2b, LA0a, LA0b, LB0a, LB0b,
          PZArz1, PZAn1, PZBrz1, PZBn1, PZArz0, PZAn0, PZBrz0, PZBn0, 6, false)

    // ---- steady loop: 42 iterations x 6 chunks (4..255) ----
    #pragma unroll 1
    for (int qq = 0; qq < 42; ++qq) {
        const int c0 = 4 + qq * 6;
        RUNCP(c0 + 0, LA0a, LA0b, LB0a, LB0b, LA1a, LA1b, LB1a, LB1b,
              PZArz0, PZAn0, PZBrz0, PZBn0, PZArz1, PZAn1, PZBrz1, PZBn1, c0 + 3, false)
        RUNCP(c0 + 1, LA1a, LA1b, LB1a, LB1b, LA2a, LA2b, LB2a, LB2b,
              PZArz1, PZAn1, PZBrz1, PZBn1, PZArz0, PZAn0, PZBrz0, PZBn0, c0 + 4, false)
        RUNCP(c0 + 2, LA2a, LA2b, LB2a, LB2b, LA0a, LA0b, LB0a, LB0b,
              PZArz0, PZAn0, PZBrz0, PZBn0, PZArz1, PZAn1, PZBrz1, PZBn1, c0 + 5, false)
        RUNCP(c0 + 3, LA0a, LA0b, LB0a, LB0b, LA1a, LA1b, LB1a, LB1b,
              PZArz1, PZAn1, PZBrz1, PZBn1, PZArz0, PZAn0, PZBrz0, PZBn0, c0 + 6, false)
        RUNCP(c0 + 4, LA1a, LA1b, LB1a, LB1b, LA2a, LA2b, LB2a, LB2b,
              PZArz0, PZAn0, PZBrz0, PZBn0, PZArz1, PZAn1, PZBrz1, PZBn1, c0 + 7, false)
        RUNCP(c0 + 5, LA2a, LA2b, LB2a, LB2b, LA0a, LA0b, LB0a, LB0b,
              PZArz1, PZAn1, PZBrz1, PZBn1, PZArz0, PZAn0, PZBrz0, PZBn0, c0 + 8, false)
    }

    // tail: 5 guarded steps, no x (layer 0 frozen; layers 1..5 finish)
    #pragma unroll
    for (int i = T_LEN; i < T_LEN + 5; ++i) stepP(i, B1R2, B1Z2, B1N2, true);

    if (l == 5) {
        out[bA] = h.x;   // layer-5 h frozen at t = T-1
        out[bB] = h.y;
    }
}

extern "C" void kernel_launch(void* const* d_in, const int* in_sizes, int n_in,
                              void* d_out, int out_size, void* d_ws, size_t ws_size,
                              hipStream_t stream) {
    const float* x     = (const float*)d_in[0];
    const float* Wih0  = (const float*)d_in[1];
    const float* Wrest = (const float*)d_in[2];
    const float* Whh   = (const float*)d_in[3];
    const float* bih   = (const float*)d_in[4];
    const float* bhh   = (const float*)d_in[5];
    float* out = (float*)d_out;

    gru_scan<<<256, 64, 0, stream>>>(x, Wih0, Wrest, Whh, bih, bhh, out);
}

// Round 15
// 148.281 us; speedup vs baseline: 1.8231x; 1.7675x over previous
//
#include <hip/hip_runtime.h>

// GRU stack, hidden_size=1, 6 layers, B=4096, T=2048, D=8.  [FINAL: r12 kernel]
// One 8-lane group per batch element: lanes 0..5 = layers (skewed pipeline).
// Layer l at iteration i handles t = i - l; prev layer's h via DPP row_shr:1.
//
// STRUCTURAL ROOFLINE NOTE: per-step wall = 173 cy, model = 170 cy chain:
// dpp(6) + fma(8) + exp2(35) + add/rcp(39) + fma(4) + exp2(35) + fma(4)
// + rcp(35) + fma(4). Exact GRU needs 4 SERIAL trans ops (n-gate contains r;
// blend needs a division). Issue trims (r9/r10), per-step fusion (r10),
// static-DPP presel (r12) all confirm non-chain work is fully hidden; 3
// attempts at cross-chain ILP (r8/r13/r14) were re-serialized by the
// compiler. Memory 4% HBM, zero LDS ops, zero conflicts -> latency-bound at
// the transcendental-chain floor: 2053 iter x 173 cy / 2.4GHz = 148 us.
//
// Pipeline: load(c+4) | dots(c+2) | presel(c+1) | run(c), register-resident.
// Layer-0 projection: distributed dots (lane j = step j), brought to lane 8g
// by STATIC row_shl:s DPP + select (no LDS, no serial DPP belt).
//
// Gate math in exp2 form, constants pre-folded:
//   sigmoid(p) = rcp(1 + exp2(c1*p)),  c1 = -log2(e)   [r gate]
//   1-sigmoid(p) = rcp(1 + exp2(cz*p)), cz = +log2(e)  [zbar]
//   merged rcp: hn = h + R*((1-h) - (1+h)*en), R = rcp((1+en)(1+ez)),
//   P = fma(en, pz1, pz1)

#define T_LEN 2048
#define T8    (T_LEN * 8)
#define NCH   256          // 8-step chunks

typedef __attribute__((ext_vector_type(2))) float v2f;

__device__ __forceinline__ float dpp_shr1(float v) {   // lane i <- lane i-1
    int i = __builtin_bit_cast(int, v);
    int r = __builtin_amdgcn_update_dpp(0, i, 0x111, 0xF, 0xF, true);
    return __builtin_bit_cast(float, r);
}

// static row_shl:S (lane i <- lane i+S), S must be a literal 1..7
#define DPPSHL(S, v) __builtin_bit_cast(float,                                \
    __builtin_amdgcn_update_dpp(0, __builtin_bit_cast(int, (v)),              \
                                0x100 | ((S) == 0 ? 1 : (S)), 0xF, 0xF, true))
#define DPPSHLX(S, v) ((S) == 0 ? (v) : DPPSHL(S, v))

__global__ __launch_bounds__(64)
__attribute__((amdgpu_waves_per_eu(1, 1)))
void gru_scan(const float* __restrict__ x,
              const float* __restrict__ Wih0,   // [3][8]
              const float* __restrict__ Wrest,  // [5][3]
              const float* __restrict__ Whh,    // [6][3]
              const float* __restrict__ bih,    // [6][3]
              const float* __restrict__ bhh,    // [6][3]
              float* __restrict__ out)          // [B]
{
    const int lane = threadIdx.x & 63;   // block = 1 wave
    const int l    = lane & 7;           // 0..5 layers; 6,7 proj helpers
    const int g    = lane >> 3;          // group (batch) within wave
    const int b    = blockIdx.x * 8 + g;

    const float c1 = -1.44269504088896340736f;   // -log2(e)  [r gate]
    const float cz =  1.44269504088896340736f;   // +log2(e)  [zbar gate]
    const float c2 = 2.0f * c1;                  // [n gate]

    const int  lidx = l < 6 ? l : 5;
    const bool lz   = (l == 0);
    const float m1  = lz ? 0.0f : 1.0f;

    const float whpr = c1 * Whh[lidx * 3 + 0];
    const float whpz = cz * Whh[lidx * 3 + 1];
    const float whpn = c2 * Whh[lidx * 3 + 2];
    const float bhpn = c2 * bhh[lidx * 3 + 2];
    const v2f  WH12 = {whpr, whpz};

    const int ir = lidx >= 1 ? lidx - 1 : 0;
    const float W1r = m1 * c1 * Wrest[ir * 3 + 0];
    const float W1z = m1 * cz * Wrest[ir * 3 + 1];
    const float W1n = m1 * c2 * Wrest[ir * 3 + 2];
    const v2f  W1rz = {W1r, W1z};
    const float B1r = c1 * (bih[lidx * 3 + 0] + bhh[lidx * 3 + 0]);
    const float B1z = cz * (bih[lidx * 3 + 1] + bhh[lidx * 3 + 1]);
    const float B1n = c2 *  bih[lidx * 3 + 2];
    const v2f  B1rz = {B1r, B1z};

    // layer-0 projection constants (uniform)
    const v2f  B0rz = {c1 * (bih[0] + bhh[0]), cz * (bih[1] + bhh[1])};
    const float B0n = c2 * bih[2];
    v2f  wrz[8];
    float wn[8];
    #pragma unroll
    for (int d = 0; d < 8; ++d) {
        wrz[d] = (v2f){c1 * Wih0[d], cz * Wih0[8 + d]};
        wn[d]  = c2 * Wih0[16 + d];
    }

    // lane j of a group loads only step j's 32B of each chunk
    const float4* xp = reinterpret_cast<const float4*>(x + (size_t)b * T8) + (lane & 7) * 2;

    // L buffers: chunk c -> slot c&3
    float4 L0a, L0b, L1a, L1b, L2a, L2b, L3a, L3b;
    // dot accumulators: chunk c -> PZ[c&1]
    v2f   PZArz, PZBrz;
    float PZAn,  PZBn;
    // preselected per-step gate bases: chunk c -> S[c&1]
    v2f   SrzA[8], SrzB[8];
    float SnA[8],  SnB[8];
    float h = 0.0f;

#define LOADL(A, B, C)                                                        \
    { const int cc_ = ((C) < NCH) ? (C) : 0;                                  \
      const float4* p_ = xp + (size_t)cc_ * 16;                               \
      A = p_[0]; B = p_[1]; }

#define GETF(S, A, B) ((S)==0?(A).x:(S)==1?(A).y:(S)==2?(A).z:(S)==3?(A).w:  \
                       (S)==4?(B).x:(S)==5?(B).y:(S)==6?(B).z:(B).w)

    // dot slice S: lane j accumulates dimension S of its step-j projection
#define DOT_SLICE(S, LA, LB, PRZ, PN)                                         \
    { const float xv_ = GETF(S, LA, LB);                                      \
      if ((S) == 0) { PRZ = wrz[0] * (v2f){xv_, xv_} + B0rz;                  \
                      PN  = fmaf(xv_, wn[0], B0n); }                          \
      else          { PRZ = wrz[S] * (v2f){xv_, xv_} + PRZ;                   \
                      PN  = fmaf(xv_, wn[S], PN); } }

    // preselect slot S: static shl:S brings proj(step S) to lane 8g; others B1
#define PRESEL(S, SRZ, SN, PRZs, PNs)                                         \
    { const float br_ = DPPSHLX(S, (PRZs).x);                                 \
      const float bz_ = DPPSHLX(S, (PRZs).y);                                 \
      const float bn_ = DPPSHLX(S, (PNs));                                    \
      SRZ[S] = (v2f){lz ? br_ : B1r, lz ? bz_ : B1z};                         \
      SN[S]  = lz ? bn_ : B1n; }

    auto step1 = [&](int i, v2f brz, float bn, bool guard) {
        const float nbr = dpp_shr1(h);

        const v2f t12 = WH12 * (v2f){h, h} + brz;
        const v2f arz = W1rz * (v2f){nbr, nbr} + t12;
        const float er = __builtin_amdgcn_exp2f(arz.x);
        const float ez = __builtin_amdgcn_exp2f(arz.y);
        const float r  = __builtin_amdgcn_rcpf(1.0f + er);
        const float pz1 = 1.0f + ez;

        const v2f tnx = (v2f){whpn, W1n} * (v2f){h, nbr} + (v2f){bhpn, bn};
        const float na = fmaf(r, tnx.x, tnx.y);
        const float en = __builtin_amdgcn_exp2f(na);

        const float P  = fmaf(en, pz1, pz1);           // (1+en)(1+ez)
        const float R  = __builtin_amdgcn_rcpf(P);     // merged z+n rcp
        const float hp1 = h + 1.0f;
        const float hm1 = 1.0f - h;
        const float q  = fmaf(-hp1, en, hm1);
        const float hn = fmaf(R, q, h);                // h + R*q

        if (guard) {
            h = ((unsigned)(i - l) < (unsigned)T_LEN) ? hn : h;
        } else {
            h = hn;
        }
    };

    // fused step: chain + dot slice (chunk c+2) + presel slot (chunk c+1)
#define STEPX(S, C, SRr, SNr, SRw, SNw, PZr_rz, PZr_n, PZw_rz, PZw_n,         \
              LNa, LNb, GD)                                                   \
    { step1((C) * 8 + (S), SRr[S], SNr[S], GD);                               \
      DOT_SLICE(S, LNa, LNb, PZw_rz, PZw_n)                                   \
      PRESEL(S, SRw, SNw, PZr_rz, PZr_n) }

#define RUN_CHUNK(C, SRr, SNr, SRw, SNw, PZr_rz, PZr_n, PZw_rz, PZw_n,        \
                  LNa, LNb, LlA, LlB, C4, GD)                                 \
    { LOADL(LlA, LlB, C4)                                                     \
      STEPX(0, C, SRr, SNr, SRw, SNw, PZr_rz, PZr_n, PZw_rz, PZw_n, LNa, LNb, GD) \
      STEPX(1, C, SRr, SNr, SRw, SNw, PZr_rz, PZr_n, PZw_rz, PZw_n, LNa, LNb, GD) \
      STEPX(2, C, SRr, SNr, SRw, SNw, PZr_rz, PZr_n, PZw_rz, PZw_n, LNa, LNb, GD) \
      STEPX(3, C, SRr, SNr, SRw, SNw, PZr_rz, PZr_n, PZw_rz, PZw_n, LNa, LNb, GD) \
      STEPX(4, C, SRr, SNr, SRw, SNw, PZr_rz, PZr_n, PZw_rz, PZw_n, LNa, LNb, GD) \
      STEPX(5, C, SRr, SNr, SRw, SNw, PZr_rz, PZr_n, PZw_rz, PZw_n, LNa, LNb, GD) \
      STEPX(6, C, SRr, SNr, SRw, SNw, PZr_rz, PZr_n, PZw_rz, PZw_n, LNa, LNb, GD) \
      STEPX(7, C, SRr, SNr, SRw, SNw, PZr_rz, PZr_n, PZw_rz, PZw_n, LNa, LNb, GD) }

    // ---- prologue: L0..L3 <- chunks 0..3; dots(0)->PZA, dots(1)->PZB;
    //      presel(0)->SA ----
    LOADL(L0a, L0b, 0) LOADL(L1a, L1b, 1) LOADL(L2a, L2b, 2) LOADL(L3a, L3b, 3)

    DOT_SLICE(0, L0a, L0b, PZArz, PZAn) DOT_SLICE(1, L0a, L0b, PZArz, PZAn)
    DOT_SLICE(2, L0a, L0b, PZArz, PZAn) DOT_SLICE(3, L0a, L0b, PZArz, PZAn)
    DOT_SLICE(4, L0a, L0b, PZArz, PZAn) DOT_SLICE(5, L0a, L0b, PZArz, PZAn)
    DOT_SLICE(6, L0a, L0b, PZArz, PZAn) DOT_SLICE(7, L0a, L0b, PZArz, PZAn)

    DOT_SLICE(0, L1a, L1b, PZBrz, PZBn) DOT_SLICE(1, L1a, L1b, PZBrz, PZBn)
    DOT_SLICE(2, L1a, L1b, PZBrz, PZBn) DOT_SLICE(3, L1a, L1b, PZBrz, PZBn)
    DOT_SLICE(4, L1a, L1b, PZBrz, PZBn) DOT_SLICE(5, L1a, L1b, PZBrz, PZBn)
    DOT_SLICE(6, L1a, L1b, PZBrz, PZBn) DOT_SLICE(7, L1a, L1b, PZBrz, PZBn)

    PRESEL(0, SrzA, SnA, PZArz, PZAn) PRESEL(1, SrzA, SnA, PZArz, PZAn)
    PRESEL(2, SrzA, SnA, PZArz, PZAn) PRESEL(3, SrzA, SnA, PZArz, PZAn)
    PRESEL(4, SrzA, SnA, PZArz, PZAn) PRESEL(5, SrzA, SnA, PZArz, PZAn)
    PRESEL(6, SrzA, SnA, PZArz, PZAn) PRESEL(7, SrzA, SnA, PZArz, PZAn)

    // ---- chunks 0..3 (chunk 0 guarded) ----
    RUN_CHUNK(0, SrzA, SnA, SrzB, SnB, PZBrz, PZBn, PZArz, PZAn, L2a, L2b, L0a, L0b, 4, true)
    RUN_CHUNK(1, SrzB, SnB, SrzA, SnA, PZArz, PZAn, PZBrz, PZBn, L3a, L3b, L1a, L1b, 5, false)
    RUN_CHUNK(2, SrzA, SnA, SrzB, SnB, PZBrz, PZBn, PZArz, PZAn, L0a, L0b, L2a, L2b, 6, false)
    RUN_CHUNK(3, SrzB, SnB, SrzA, SnA, PZArz, PZAn, PZBrz, PZBn, L1a, L1b, L3a, L3b, 7, false)

    #pragma unroll 1
    for (int q = 1; q < 64; ++q) {
        const int c0 = q * 4;
        RUN_CHUNK(c0 + 0, SrzA, SnA, SrzB, SnB, PZBrz, PZBn, PZArz, PZAn, L2a, L2b, L0a, L0b, c0 + 4, false)
        RUN_CHUNK(c0 + 1, SrzB, SnB, SrzA, SnA, PZArz, PZAn, PZBrz, PZBn, L3a, L3b, L1a, L1b, c0 + 5, false)
        RUN_CHUNK(c0 + 2, SrzA, SnA, SrzB, SnB, PZBrz, PZBn, PZArz, PZAn, L0a, L0b, L2a, L2b, c0 + 6, false)
        RUN_CHUNK(c0 + 3, SrzB, SnB, SrzA, SnA, PZArz, PZAn, PZBrz, PZBn, L1a, L1b, L3a, L3b, c0 + 7, false)
    }

    // tail: 5 guarded steps, no x (layer 0 frozen; layers 1..5 finish)
    #pragma unroll
    for (int i = T_LEN; i < T_LEN + 5; ++i) step1(i, B1rz, B1n, true);

    if (l == 5) out[b] = h;          // layer-5 h frozen at t = T-1
}

extern "C" void kernel_launch(void* const* d_in, const int* in_sizes, int n_in,
                              void* d_out, int out_size, void* d_ws, size_t ws_size,
                              hipStream_t stream) {
    const float* x     = (const float*)d_in[0];
    const float* Wih0  = (const float*)d_in[1];
    const float* Wrest = (const float*)d_in[2];
    const float* Whh   = (const float*)d_in[3];
    const float* bih   = (const float*)d_in[4];
    const float* bhh   = (const float*)d_in[5];
    float* out = (float*)d_out;

    gru_scan<<<512, 64, 0, stream>>>(x, Wih0, Wrest, Whh, bih, bhh, out);
}